// Round 2
// baseline (74.214 us; speedup 1.0000x reference)
//
#include <hip/hip_runtime.h>

typedef _Float16 half8 __attribute__((ext_vector_type(8)));
typedef float   float4_t __attribute__((ext_vector_type(4)));

#define TH 16
#define TW 16

__global__ __launch_bounds__(256) void depth_up_fused(
    const float* __restrict__ depth,
    const float* __restrict__ cv,
    const float* __restrict__ w1,   // [8,8,3,3]
    const float* __restrict__ b1,   // [8]
    const float* __restrict__ w2,   // [36,8]
    const float* __restrict__ b2,   // [36]
    float* __restrict__ out)        // [N, 1024, 1280]
{
    const int H = 512, W = 640;
    const size_t HW = (size_t)H * W;
    const int n  = blockIdx.z;
    const int h0 = blockIdx.y * TH;
    const int w0 = blockIdx.x * TW;
    const int tid  = threadIdx.x;      // 0..255
    const int lane = tid & 63;
    const int wv   = tid >> 6;         // wave 0..3
    const int o    = lane & 15;        // MFMA col (out channel) / pixel col
    const int krow = lane >> 4;        // MFMA k-group 0..3

    // LDS: cv tile fp16 [18 rows][18 cols][8 ch] (16B per pixel), depth tile f32,
    //      X transpose buffer f32 [wave][64 pix][8 ch]
    __shared__ half8   cvh8[18 * 18];
    __shared__ float   sd[18 * 19];
    __shared__ float4_t xh4[4 * 64 * 2];

    const float* __restrict__ cvn = cv + (size_t)n * 8 * HW;
    const float* __restrict__ dn  = depth + (size_t)n * HW;

    // ---- stage cv (as fp16x8) + depth tiles with zero halo ----
    for (int i = tid; i < 324; i += 256) {
        const int r = i / 18;
        const int c = i - r * 18;
        const int gh = h0 + r - 1;
        const int gw = w0 + c - 1;
        const bool ok = ((unsigned)gh < (unsigned)H) && ((unsigned)gw < (unsigned)W);
        const size_t off = (size_t)gh * W + gw;
        half8 hv;
        #pragma unroll
        for (int ch = 0; ch < 8; ++ch) {
            const float v = ok ? cvn[ch * HW + off] : 0.0f;
            hv[ch] = (_Float16)v;
        }
        cvh8[r * 18 + c] = hv;
        sd[r * 19 + c] = ok ? dn[off] : 0.0f;
    }

    // ---- pack conv1 weights into B fragments (per lane, L1-hot after warmup) ----
    // K order: k = tap*8 + c ; B[k][och] = w1[och][c][tap]
    half8 bfrag[3];
    #pragma unroll
    for (int ki = 0; ki < 3; ++ki) {
        const int tap = 4 * ki + krow;
        #pragma unroll
        for (int j = 0; j < 8; ++j) {
            const float wval = (tap < 9 && o < 8) ? w1[(o * 8 + j) * 9 + tap] : 0.0f;
            bfrag[ki][j] = (_Float16)wval;
        }
    }
    const float vb1 = (o < 8) ? b1[o] : 0.0f;

    // per-lane A-fragment byte offsets (group 0); group g adds g*288
    int aoff[3];
    #pragma unroll
    for (int ki = 0; ki < 3; ++ki) {
        const int tap = 4 * ki + krow;
        const int t   = tap > 8 ? 8 : tap;       // clamp (B rows are 0 there)
        const int ky  = t / 3;
        const int kx  = t - 3 * ky;
        aoff[ki] = ((wv * 4 + ky) * 18 + (o + kx)) * 16;
    }

    __syncthreads();

    // ---- conv1 via MFMA: D[16 pix][16 och] per group, 4 groups x 3 K-steps ----
    float4_t acc[4];
    const float4_t zero4 = {0.0f, 0.0f, 0.0f, 0.0f};
    #pragma unroll
    for (int g = 0; g < 4; ++g) acc[g] = zero4;

    const char* cvbase = (const char*)cvh8;
    #pragma unroll
    for (int ki = 0; ki < 3; ++ki) {
        #pragma unroll
        for (int g = 0; g < 4; ++g) {
            const half8 afrag = *(const half8*)(cvbase + aoff[ki] + g * 288);
            acc[g] = __builtin_amdgcn_mfma_f32_16x16x32_f16(afrag, bfrag[ki], acc[g], 0, 0, 0);
        }
    }

    // ---- bias + relu, transpose via LDS so each lane owns one pixel ----
    float* xhf = (float*)xh4;
    if (o < 8) {
        #pragma unroll
        for (int g = 0; g < 4; ++g) {
            #pragma unroll
            for (int r = 0; r < 4; ++r) {
                const float xv = fmaxf(acc[g][r] + vb1, 0.0f);
                const int pix = g * 16 + krow * 4 + r;   // D row = (lane>>4)*4 + reg
                xhf[(wv * 64 + pix) * 8 + o] = xv;
            }
        }
    }
    __syncthreads();

    float x[8];
    {
        const float4_t x0 = xh4[(wv * 64 + lane) * 2 + 0];
        const float4_t x1 = xh4[(wv * 64 + lane) * 2 + 1];
        #pragma unroll
        for (int c = 0; c < 4; ++c) { x[c] = x0[c]; x[4 + c] = x1[c]; }
    }

    // ---- conv2: 1x1, 8->36 (f32 VALU, scalar-loaded weights), *0.25 ----
    float mask[36];
    #pragma unroll
    for (int m = 0; m < 36; ++m) {
        float s = b2[m];
        #pragma unroll
        for (int c = 0; c < 8; ++c) s += x[c] * w2[m * 8 + c];
        mask[m] = 0.25f * s;
    }

    // ---- depth 3x3 patch for this lane's pixel ----
    const int prow = wv * 4 + krow;
    const int pcol = o;
    float patch[9];
    #pragma unroll
    for (int ky = 0; ky < 3; ++ky)
        #pragma unroll
        for (int kx = 0; kx < 3; ++kx)
            patch[ky * 3 + kx] = sd[(prow + ky) * 19 + (pcol + kx)];

    // ---- 4 softmaxes over 9 taps + weighted sum ----
    float res[4];
    #pragma unroll
    for (int q = 0; q < 4; ++q) {
        float mx = mask[q];
        #pragma unroll
        for (int k = 1; k < 9; ++k) mx = fmaxf(mx, mask[k * 4 + q]);
        float sum = 0.0f, r = 0.0f;
        #pragma unroll
        for (int k = 0; k < 9; ++k) {
            const float e = __expf(mask[k * 4 + q] - mx);
            sum += e;
            r += e * patch[k];
        }
        res[q] = r * __builtin_amdgcn_rcpf(sum);
    }

    // ---- store 2x2 output pixels ----
    const int h = h0 + prow;
    const int w = w0 + pcol;
    float* op = out + ((size_t)n * 1024 + (size_t)(2 * h)) * 1280 + (size_t)(2 * w);
    *reinterpret_cast<float2*>(op)        = make_float2(res[0], res[1]);
    *reinterpret_cast<float2*>(op + 1280) = make_float2(res[2], res[3]);
}

extern "C" void kernel_launch(void* const* d_in, const int* in_sizes, int n_in,
                              void* d_out, int out_size, void* d_ws, size_t ws_size,
                              hipStream_t stream) {
    (void)in_sizes; (void)n_in; (void)out_size; (void)d_ws; (void)ws_size;
    const float* depth = (const float*)d_in[0];
    const float* cv    = (const float*)d_in[1];
    const float* w1    = (const float*)d_in[2];
    const float* b1    = (const float*)d_in[3];
    const float* w2    = (const float*)d_in[4];
    const float* b2    = (const float*)d_in[5];
    float* out = (float*)d_out;

    dim3 grid(640 / TW, 512 / TH, 4);
    dim3 block(256);
    hipLaunchKernelGGL(depth_up_fused, grid, block, 0, stream,
                       depth, cv, w1, b1, w2, b2, out);
}

// Round 3
// 69.896 us; speedup vs baseline: 1.0618x; 1.0618x over previous
//
#include <hip/hip_runtime.h>

typedef _Float16 half8 __attribute__((ext_vector_type(8)));
typedef float   float4_t __attribute__((ext_vector_type(4)));

#define SH 4            // output rows per block
#define SW 320          // output cols per block
#define CW (SW + 2)     // staged cv cols (x-halo)
#define NR (SH + 2)     // staged rows (y-halo)

__global__ __launch_bounds__(256) void depth_up_fused(
    const float* __restrict__ depth,
    const float* __restrict__ cv,
    const float* __restrict__ w1,   // [8,8,3,3]
    const float* __restrict__ b1,   // [8]
    const float* __restrict__ w2,   // [36,8]
    const float* __restrict__ b2,   // [36]
    float* __restrict__ out)        // [N, 1024, 1280]
{
    const int H = 512, W = 640;
    const size_t HW = (size_t)H * W;
    const int n  = blockIdx.z;
    const int h0 = blockIdx.y * SH;
    const int cb = blockIdx.x * SW;
    const int tid  = threadIdx.x;      // 0..255 (4 waves)
    const int lane = tid & 63;
    const int wv   = tid >> 6;         // wave = output row within strip
    const int o    = lane & 15;        // MFMA A-row (pixel col) / D-col (och)
    const int krow = lane >> 4;

    __shared__ half8    s_cv[NR * CW];     // 30,912 B: [row][col][8ch] fp16
    __shared__ _Float16 s_x[4 * 64 * 8];   //  4,096 B: per-wave transpose buf

    const float* __restrict__ cvn = cv + (size_t)n * 8 * HW;
    const float* __restrict__ dn  = depth + (size_t)n * HW;

    // ---- stage cv strip (contiguous 256B-per-wave-per-channel reads) ----
    for (int i = tid; i < NR * CW; i += 256) {
        const int r = i / CW;
        const int c = i - r * CW;
        const int gh = h0 + r - 1;
        const int gw = cb + c - 1;
        half8 hv = {};
        if ((unsigned)gh < (unsigned)H && (unsigned)gw < (unsigned)W) {
            const float* p = cvn + (size_t)gh * W + gw;
            #pragma unroll
            for (int ch = 0; ch < 8; ++ch)
                hv[ch] = (_Float16)p[(size_t)ch * HW];
        }
        s_cv[i] = hv;
    }

    // ---- conv1 weight B-fragments: k = tap*8 + c, B[k][och] = w1[och][c][tap] ----
    half8 bfrag[3];
    #pragma unroll
    for (int ki = 0; ki < 3; ++ki) {
        const int tap = 4 * ki + krow;
        #pragma unroll
        for (int j = 0; j < 8; ++j)
            bfrag[ki][j] = (tap < 9 && o < 8) ? (_Float16)w1[(o * 8 + j) * 9 + tap]
                                              : (_Float16)0.0f;
    }
    const float vb1 = (o < 8) ? b1[o] : 0.0f;

    // per-lane LDS byte offsets for the 3 K-steps (chunk/group offsets are imm)
    int aoff[3];
    #pragma unroll
    for (int ki = 0; ki < 3; ++ki) {
        const int tap0 = 4 * ki + krow;
        const int tap  = tap0 > 8 ? 8 : tap0;     // clamped; B rows are zero there
        const int ky   = tap / 3;
        const int kx   = tap - 3 * ky;
        aoff[ki] = ((wv + ky) * CW + o + kx) * 16;
    }

    __syncthreads();

    _Float16* xw = s_x + wv * 64 * 8;
    const char* cvb = (const char*)s_cv;
    const float4_t zero4 = {0.0f, 0.0f, 0.0f, 0.0f};

    // ---- each wave: its row, 5 chunks of 64 pixels ----
    for (int cc = 0; cc < 5; ++cc) {
        float4_t acc[4];
        #pragma unroll
        for (int g = 0; g < 4; ++g) acc[g] = zero4;

        #pragma unroll
        for (int ki = 0; ki < 3; ++ki) {
            #pragma unroll
            for (int g = 0; g < 4; ++g) {
                const half8 a = *(const half8*)(cvb + aoff[ki] + (cc * 64 + g * 16) * 16);
                acc[g] = __builtin_amdgcn_mfma_f32_16x16x32_f16(a, bfrag[ki], acc[g], 0, 0, 0);
            }
        }

        // bias+relu, per-wave fp16 transpose so each lane owns one pixel
        if (o < 8) {
            #pragma unroll
            for (int g = 0; g < 4; ++g)
                #pragma unroll
                for (int r = 0; r < 4; ++r)
                    xw[(g * 16 + krow * 4 + r) * 8 + o] =
                        (_Float16)fmaxf(acc[g][r] + vb1, 0.0f);
        }
        asm volatile("s_waitcnt lgkmcnt(0)" ::: "memory");
        __builtin_amdgcn_sched_barrier(0);

        const half8 xv = *(const half8*)(xw + lane * 8);
        float x[8];
        #pragma unroll
        for (int c = 0; c < 8; ++c) x[c] = (float)xv[c];

        // conv2: 1x1, 8->36, *0.25 (scalar-loaded weights)
        float mask[36];
        #pragma unroll
        for (int m = 0; m < 36; ++m) {
            float s = b2[m];
            #pragma unroll
            for (int c = 0; c < 8; ++c) s += x[c] * w2[m * 8 + c];
            mask[m] = 0.25f * s;
        }

        // depth 3x3 patch straight from global (L1-resident rows)
        const int prow = h0 + wv;
        const int pcol = cb + cc * 64 + lane;
        float patch[9];
        #pragma unroll
        for (int ky = 0; ky < 3; ++ky) {
            #pragma unroll
            for (int kx = 0; kx < 3; ++kx) {
                const int gh = prow + ky - 1;
                const int gw = pcol + kx - 1;
                patch[ky * 3 + kx] =
                    ((unsigned)gh < (unsigned)H && (unsigned)gw < (unsigned)W)
                        ? dn[gh * W + gw] : 0.0f;
            }
        }

        // 4 softmaxes over 9 taps + weighted sum
        float res[4];
        #pragma unroll
        for (int q = 0; q < 4; ++q) {
            float mx = mask[q];
            #pragma unroll
            for (int k = 1; k < 9; ++k) mx = fmaxf(mx, mask[k * 4 + q]);
            float sum = 0.0f, rr = 0.0f;
            #pragma unroll
            for (int k = 0; k < 9; ++k) {
                const float e = __expf(mask[k * 4 + q] - mx);
                sum += e;
                rr += e * patch[k];
            }
            res[q] = rr * __builtin_amdgcn_rcpf(sum);
        }

        // store: full-row contiguous (512B per wave-store)
        float* op = out + ((size_t)n * 1024 + (size_t)(2 * prow)) * 1280 + (size_t)(2 * pcol);
        *reinterpret_cast<float2*>(op)        = make_float2(res[0], res[1]);
        *reinterpret_cast<float2*>(op + 1280) = make_float2(res[2], res[3]);
    }
}

extern "C" void kernel_launch(void* const* d_in, const int* in_sizes, int n_in,
                              void* d_out, int out_size, void* d_ws, size_t ws_size,
                              hipStream_t stream) {
    (void)in_sizes; (void)n_in; (void)out_size; (void)d_ws; (void)ws_size;
    const float* depth = (const float*)d_in[0];
    const float* cv    = (const float*)d_in[1];
    const float* w1    = (const float*)d_in[2];
    const float* b1    = (const float*)d_in[3];
    const float* w2    = (const float*)d_in[4];
    const float* b2    = (const float*)d_in[5];
    float* out = (float*)d_out;

    dim3 grid(640 / SW, 512 / SH, 4);   // (2, 128, 4) = 1024 blocks
    dim3 block(256);
    hipLaunchKernelGGL(depth_up_fused, grid, block, 0, stream,
                       depth, cv, w1, b1, w2, b2, out);
}

// Round 4
// 54.220 us; speedup vs baseline: 1.3688x; 1.2891x over previous
//
#include <hip/hip_runtime.h>

typedef _Float16 half8  __attribute__((ext_vector_type(8)));
typedef float    float4_t __attribute__((ext_vector_type(4)));

#define SH 4
#define SW 320
#define CW (SW + 2)   // 322 staged cv cols
#define NR (SH + 2)   // 6 staged rows
#define DW 323        // depth LDS row stride (floats, odd for bank spread)

__device__ __forceinline__ float fexp2(float x) {
    float r;
    asm volatile("v_exp_f32 %0, %1" : "=v"(r) : "v"(x));
    return r;
}

__global__ __launch_bounds__(256) void depth_up_fused(
    const float* __restrict__ depth,
    const float* __restrict__ cv,
    const float* __restrict__ w1,   // [8,8,3,3]
    const float* __restrict__ b1,   // [8]
    const float* __restrict__ w2,   // [36,8]
    const float* __restrict__ b2,   // [36]
    float* __restrict__ out)        // [N, 1024, 1280]
{
    const int H = 512, W = 640;
    const size_t HW = (size_t)H * W;
    const int n  = blockIdx.z;
    const int h0 = blockIdx.y * SH;
    const int cb = blockIdx.x * SW;
    const int tid  = threadIdx.x;
    const int lane = tid & 63;
    const int wv   = tid >> 6;       // wave = row within strip
    const int o    = lane & 15;
    const int krow = lane >> 4;
    const int u    = o >> 2;         // tap-group
    const int q    = o & 3;          // softmax column

    __shared__ half8 s_cv[NR * CW];  // 30,912 B
    __shared__ float s_d[NR * DW];   //  7,752 B

    const float* __restrict__ cvn = cv + (size_t)n * 8 * HW;
    const float* __restrict__ dn  = depth + (size_t)n * HW;

    // ---- stage cv (fp16x8, [row][col][ch]) + depth (f32) with zero halo ----
    for (int i = tid; i < NR * CW; i += 256) {
        const int r = i / CW;
        const int c = i - r * CW;
        const int gh = h0 + r - 1;
        const int gw = cb + c - 1;
        half8 hv = {};
        float dv = 0.0f;
        if ((unsigned)gh < (unsigned)H && (unsigned)gw < (unsigned)W) {
            const float* p = cvn + (size_t)gh * W + gw;
            #pragma unroll
            for (int ch = 0; ch < 8; ++ch) hv[ch] = (_Float16)p[(size_t)ch * HW];
            dv = dn[(size_t)gh * W + gw];
        }
        s_cv[i] = hv;
        s_d[r * DW + c] = dv;
    }

    // ---- conv1 weights as A-fragments: A1[row=och][k], k = tap*8 + c ----
    half8 a1[3];
    #pragma unroll
    for (int ki = 0; ki < 3; ++ki) {
        const int tap = 4 * ki + krow;
        #pragma unroll
        for (int j = 0; j < 8; ++j)
            a1[ki][j] = (tap < 9 && o < 8) ? (_Float16)w1[(o * 8 + j) * 9 + tap]
                                           : (_Float16)0.0f;
    }
    // cv B-fragment per-lane base byte offsets (same bytes as r3)
    int aoff[3];
    #pragma unroll
    for (int ki = 0; ki < 3; ++ki) {
        const int tap0 = 4 * ki + krow;
        const int tap  = tap0 > 8 ? 8 : tap0;
        const int ky   = tap / 3;
        const int kx   = tap - 3 * ky;
        aoff[ki] = ((wv + ky) * CW + o + kx) * 16;
    }
    // b1 for this lane's 4 och (valid for krow<2; others unused junk)
    const float4_t b1q = *reinterpret_cast<const float4_t*>(b1 + (krow & 1) * 4);

    // ---- conv2 weights as B-fragments (only k=0..7 rows live -> krow==0) ----
    half8 b2f[3] = {};
    if (krow == 0) {
        #pragma unroll
        for (int t = 0; t < 3; ++t) {
            const int m = (o + 16 * t) > 35 ? 35 : (o + 16 * t);
            const float4_t wlo = *reinterpret_cast<const float4_t*>(w2 + m * 8);
            const float4_t whi = *reinterpret_cast<const float4_t*>(w2 + m * 8 + 4);
            #pragma unroll
            for (int j = 0; j < 4; ++j) {
                b2f[t][j]     = (_Float16)wlo[j];
                b2f[t][4 + j] = (_Float16)whi[j];
            }
        }
    }
    // 0.25 * log2(e) folded scale; bias pre-scaled into log2 domain
    const float C = 0.25f * 1.44269504f;
    float b2q[3];
    #pragma unroll
    for (int t = 0; t < 3; ++t) {
        const int m = (o + 16 * t) > 35 ? 35 : (o + 16 * t);
        b2q[t] = C * b2[m];
    }
    const bool t2ok = (u == 0);

    // patch tap byte-offsets in s_d (lane-constant): taps {u, u+4, 8}
    int poff[3];
    {
        const int taps[3] = {u, u + 4, 8};
        #pragma unroll
        for (int t = 0; t < 3; ++t) {
            const int ky = taps[t] / 3;
            const int kx = taps[t] - 3 * ky;
            poff[t] = ((wv + ky) * DW + kx) * 4;
        }
    }

    __syncthreads();

    const char* cvb = (const char*)s_cv;
    const char* sdb = (const char*)s_d;
    const float4_t zero4 = {0.0f, 0.0f, 0.0f, 0.0f};

    // ---- 20 sets of 16 pixels per wave-row; no barriers, no LDS round trips ----
    for (int ps = 0; ps < SW / 16; ++ps) {
        // conv1: D1[och][pix]  (A = weights, B = cv tile)
        float4_t acc1 = zero4;
        #pragma unroll
        for (int ki = 0; ki < 3; ++ki) {
            const half8 bcv = *(const half8*)(cvb + aoff[ki] + ps * 256);
            acc1 = __builtin_amdgcn_mfma_f32_16x16x32_f16(a1[ki], bcv, acc1, 0, 0, 0);
        }

        // X = relu(acc1 + b1); pack to fp16; xor-16 exchange completes A2 (k=0..7)
        union { half8 v; uint32_t u32[4]; } a2;
        #pragma unroll
        for (int r = 0; r < 4; ++r)
            a2.v[r] = (_Float16)fmaxf(acc1[r] + b1q[r], 0.0f);
        const uint32_t p0 = (uint32_t)__shfl_xor((int)a2.u32[0], 16);
        const uint32_t p1 = (uint32_t)__shfl_xor((int)a2.u32[1], 16);
        a2.u32[2] = p0;
        a2.u32[3] = p1;

        // conv2: D2[pix][m], 3 m-tiles
        float4_t d2[3];
        #pragma unroll
        for (int t = 0; t < 3; ++t)
            d2[t] = __builtin_amdgcn_mfma_f32_16x16x32_f16(a2.v, b2f[t], zero4, 0, 0, 0);

        // mask logits in log2 domain: ml[t][r] = C*d2 + C*b2
        float ml0[4], ml1[4], ml2[4], mx[4];
        #pragma unroll
        for (int r = 0; r < 4; ++r) {
            ml0[r] = fmaf(d2[0][r], C, b2q[0]);
            ml1[r] = fmaf(d2[1][r], C, b2q[1]);
            ml2[r] = t2ok ? fmaf(d2[2][r], C, b2q[2]) : -3.0e38f;
            mx[r]  = fmaxf(fmaxf(ml0[r], ml1[r]), ml2[r]);
        }
        // butterfly max over the 4 tap-group lanes (xor 4, xor 8)
        #pragma unroll
        for (int r = 0; r < 4; ++r) mx[r] = fmaxf(mx[r], __shfl_xor(mx[r], 4));
        #pragma unroll
        for (int r = 0; r < 4; ++r) mx[r] = fmaxf(mx[r], __shfl_xor(mx[r], 8));

        // exps + local weighted sums (patch from depth LDS)
        float se[4], sp[4];
        const int cbase = (ps * 16 + 4 * krow) * 4;
        #pragma unroll
        for (int r = 0; r < 4; ++r) {
            const float e0 = fexp2(ml0[r] - mx[r]);
            const float e1 = fexp2(ml1[r] - mx[r]);
            const float e2 = fexp2(ml2[r] - mx[r]);   // -3e38 path -> 0
            const float pt0 = *(const float*)(sdb + poff[0] + cbase + r * 4);
            const float pt1 = *(const float*)(sdb + poff[1] + cbase + r * 4);
            const float pt2 = *(const float*)(sdb + poff[2] + cbase + r * 4);
            se[r] = e0 + e1 + e2;
            sp[r] = e0 * pt0 + e1 * pt1 + e2 * pt2;
        }
        // butterfly sums
        #pragma unroll
        for (int r = 0; r < 4; ++r) { se[r] += __shfl_xor(se[r], 4); sp[r] += __shfl_xor(sp[r], 4); }
        #pragma unroll
        for (int r = 0; r < 4; ++r) { se[r] += __shfl_xor(se[r], 8); sp[r] += __shfl_xor(sp[r], 8); }

        float res[4];
        #pragma unroll
        for (int r = 0; r < 4; ++r) res[r] = sp[r] * __builtin_amdgcn_rcpf(se[r]);

        // each lane stores its unique (pixel = 4*krow + u, q) output
        const float v01 = (u & 1) ? res[1] : res[0];
        const float v23 = (u & 1) ? res[3] : res[2];
        const float val = (u & 2) ? v23 : v01;
        const int prow = h0 + wv;
        const int pcol = cb + ps * 16 + 4 * krow + u;
        out[((size_t)n * 1024 + (size_t)(2 * prow + (q >> 1))) * 1280
            + (size_t)(2 * pcol + (q & 1))] = val;
    }
}

extern "C" void kernel_launch(void* const* d_in, const int* in_sizes, int n_in,
                              void* d_out, int out_size, void* d_ws, size_t ws_size,
                              hipStream_t stream) {
    (void)in_sizes; (void)n_in; (void)out_size; (void)d_ws; (void)ws_size;
    const float* depth = (const float*)d_in[0];
    const float* cv    = (const float*)d_in[1];
    const float* w1    = (const float*)d_in[2];
    const float* b1    = (const float*)d_in[3];
    const float* w2    = (const float*)d_in[4];
    const float* b2    = (const float*)d_in[5];
    float* out = (float*)d_out;

    dim3 grid(640 / SW, 512 / SH, 4);   // (2, 128, 4) = 1024 blocks
    dim3 block(256);
    hipLaunchKernelGGL(depth_up_fused, grid, block, 0, stream,
                       depth, cv, w1, b1, w2, b2, out);
}